// Round 3
// baseline (1178.916 us; speedup 1.0000x reference)
//
#include <hip/hip_runtime.h>
#include <math.h>

#define BB 32
#define LL 2048
#define EE 512
#define HH 512

typedef __bf16 bf16_t;
typedef bf16_t bf16x8 __attribute__((ext_vector_type(8)));
typedef float f32x4 __attribute__((ext_vector_type(4)));
typedef unsigned short u16x8 __attribute__((ext_vector_type(8)));

__device__ __forceinline__ unsigned short f2bf(float f) {
  unsigned int u = __builtin_bit_cast(unsigned int, f);
  unsigned int r = (u + 0x7FFFu + ((u >> 16) & 1u)) >> 16;  // RNE
  return (unsigned short)r;
}
__device__ __forceinline__ float bf2f(unsigned short s) {
  unsigned int u = ((unsigned int)s) << 16;
  return __builtin_bit_cast(float, u);
}
__device__ __forceinline__ bf16x8 ld_frag(const unsigned short* p) {
  u16x8 raw = *(const u16x8*)p;
  return __builtin_bit_cast(bf16x8, raw);
}
__device__ __forceinline__ float tanh_fast(float x) {
  x = fminf(fmaxf(x, -15.f), 15.f);
  float e2 = __expf(2.f * x);
  return (e2 - 1.f) / (e2 + 1.f);
}

// ---------------- prep: transpose + fp32->bf16 convert of Wh, Wc ----------------
// WhT[h][e] = Wh[e][h];  WcT[e][h] = Wc[h][e]   (both 512x512)
__global__ __launch_bounds__(256) void prep_w(
    const float* __restrict__ Wh, const float* __restrict__ Wc,
    unsigned short* __restrict__ WhT, unsigned short* __restrict__ WcT)
{
  const float* src = blockIdx.y ? Wc : Wh;
  unsigned short* dst = blockIdx.y ? WcT : WhT;
  const int tr = (blockIdx.x >> 3) * 64;
  const int tc = (blockIdx.x & 7) * 64;
  const int tid = threadIdx.x;
  __shared__ float tile[64][65];
  for (int i = tid; i < 64 * 16; i += 256) {
    const int r = i >> 4, c4 = (i & 15) << 2;
    const float4 v = *(const float4*)(src + (size_t)(tr + r) * 512 + tc + c4);
    tile[r][c4 + 0] = v.x; tile[r][c4 + 1] = v.y;
    tile[r][c4 + 2] = v.z; tile[r][c4 + 3] = v.w;
  }
  __syncthreads();
  for (int i = tid; i < 64 * 16; i += 256) {
    const int r = i >> 4, c4 = (i & 15) << 2;
    ushort4 pk;
    pk.x = f2bf(tile[c4 + 0][r]); pk.y = f2bf(tile[c4 + 1][r]);
    pk.z = f2bf(tile[c4 + 2][r]); pk.w = f2bf(tile[c4 + 3][r]);
    *(ushort4*)(dst + (size_t)(tc + r) * 512 + tr + c4) = pk;
  }
}

// ---------------- main: per-(b,chunk) fused GEMM1+tanh+GEMM2+online-softmax ----------------
__global__ __launch_bounds__(256, 2) void attn_main(
    const float* __restrict__ enc, const int* __restrict__ lens,
    const unsigned short* __restrict__ WhT, const float* __restrict__ bh,
    const unsigned short* __restrict__ WcT,
    float* __restrict__ pm, float* __restrict__ ps, float* __restrict__ po,
    int C, int Lc)
{
  const int c = blockIdx.x;
  const int b = blockIdx.y;
  const int n = lens[b];
  const int l0 = c * Lc;
  const int nvalid = min(n - l0, Lc);
  if (nvalid <= 0) return;

  const int tid  = threadIdx.x;
  const int wave = tid >> 6;
  const int lane = tid & 63;
  const int quad = lane >> 4;
  const int l15  = lane & 15;
  const int wbase = wave * 128;

  __shared__ __align__(16) unsigned short encA[32 * 520];
  __shared__ __align__(16) unsigned short hS[32 * 520];
  __shared__ __align__(16) float bhS[512];

  float stM[8], stS[8], stO[8];
#pragma unroll
  for (int et = 0; et < 8; et++) { stM[et] = -1e30f; stS[et] = 0.f; stO[et] = 0.f; }

  bhS[tid] = bh[tid];
  bhS[tid + 256] = bh[tid + 256];

  for (int r0 = 0; r0 < nvalid; r0 += 32) {
    // ---- stage enc tile -> bf16 LDS ----
    const float* encRow = enc + ((size_t)b * LL + l0 + r0) * EE;
    for (int i = tid; i < 32 * 128; i += 256) {
      const int m = i >> 7, e4 = (i & 127) << 2;
      const float4 v = *(const float4*)(encRow + (size_t)m * EE + e4);
      ushort4 pk;
      pk.x = f2bf(v.x); pk.y = f2bf(v.y); pk.z = f2bf(v.z); pk.w = f2bf(v.w);
      *(ushort4*)&encA[m * 520 + e4] = pk;
    }
    __syncthreads();

    // ---- GEMM1': hT[128 x 32] per wave = WhT (A, L2) @ encT (B, LDS) ----
    f32x4 acc1[8][2];
#pragma unroll
    for (int ht = 0; ht < 8; ht++)
      for (int mt = 0; mt < 2; mt++) acc1[ht][mt] = (f32x4){0.f, 0.f, 0.f, 0.f};
    {
      const unsigned short* aBase = WhT + (size_t)(wbase + l15) * 512 + quad * 8;
      bf16x8 aP[8], aQ[8];
#pragma unroll
      for (int ht = 0; ht < 8; ht++) aP[ht] = ld_frag(aBase + ht * 8192);
#pragma unroll
      for (int kk = 0; kk < 8; kk++) {
        const int k0 = kk * 64;
        // prefetch k0+32 while computing with aP
#pragma unroll
        for (int ht = 0; ht < 8; ht++) aQ[ht] = ld_frag(aBase + ht * 8192 + k0 + 32);
        {
          bf16x8 b0 = ld_frag(&encA[l15 * 520 + k0 + quad * 8]);
          bf16x8 b1 = ld_frag(&encA[(16 + l15) * 520 + k0 + quad * 8]);
#pragma unroll
          for (int ht = 0; ht < 8; ht++) {
            acc1[ht][0] = __builtin_amdgcn_mfma_f32_16x16x32_bf16(aP[ht], b0, acc1[ht][0], 0, 0, 0);
            acc1[ht][1] = __builtin_amdgcn_mfma_f32_16x16x32_bf16(aP[ht], b1, acc1[ht][1], 0, 0, 0);
          }
        }
        if (kk < 7) {
#pragma unroll
          for (int ht = 0; ht < 8; ht++) aP[ht] = ld_frag(aBase + ht * 8192 + k0 + 64);
        }
        {
          bf16x8 b0 = ld_frag(&encA[l15 * 520 + k0 + 32 + quad * 8]);
          bf16x8 b1 = ld_frag(&encA[(16 + l15) * 520 + k0 + 32 + quad * 8]);
#pragma unroll
          for (int ht = 0; ht < 8; ht++) {
            acc1[ht][0] = __builtin_amdgcn_mfma_f32_16x16x32_bf16(aQ[ht], b0, acc1[ht][0], 0, 0, 0);
            acc1[ht][1] = __builtin_amdgcn_mfma_f32_16x16x32_bf16(aQ[ht], b1, acc1[ht][1], 0, 0, 0);
          }
        }
      }
    }

    // ---- bias + tanh, pack 4 consecutive h -> one 8B LDS write of h[m][h] ----
#pragma unroll
    for (int ht = 0; ht < 8; ht++) {
      const f32x4 bv = *(const f32x4*)&bhS[wbase + ht * 16 + quad * 4];
#pragma unroll
      for (int mt = 0; mt < 2; mt++) {
        ushort4 pk;
        pk.x = f2bf(tanh_fast(acc1[ht][mt][0] + bv[0]));
        pk.y = f2bf(tanh_fast(acc1[ht][mt][1] + bv[1]));
        pk.z = f2bf(tanh_fast(acc1[ht][mt][2] + bv[2]));
        pk.w = f2bf(tanh_fast(acc1[ht][mt][3] + bv[3]));
        *(ushort4*)&hS[(mt * 16 + l15) * 520 + wbase + ht * 16 + quad * 4] = pk;
      }
    }
    __syncthreads();

    // ---- GEMM2: logits[32 x E] = h (A, LDS) @ Wc (B = WcT, L2) ----
    f32x4 acc2[2][8];
#pragma unroll
    for (int mt = 0; mt < 2; mt++)
      for (int et = 0; et < 8; et++) acc2[mt][et] = (f32x4){0.f, 0.f, 0.f, 0.f};
    {
      const unsigned short* bBase = WcT + (size_t)(wbase + l15) * 512 + quad * 8;
      bf16x8 bP[8], bQ[8];
#pragma unroll
      for (int et = 0; et < 8; et++) bP[et] = ld_frag(bBase + et * 8192);
#pragma unroll
      for (int kk = 0; kk < 8; kk++) {
        const int k0 = kk * 64;
#pragma unroll
        for (int et = 0; et < 8; et++) bQ[et] = ld_frag(bBase + et * 8192 + k0 + 32);
        {
          bf16x8 a0 = ld_frag(&hS[l15 * 520 + k0 + quad * 8]);
          bf16x8 a1 = ld_frag(&hS[(16 + l15) * 520 + k0 + quad * 8]);
#pragma unroll
          for (int et = 0; et < 8; et++) {
            acc2[0][et] = __builtin_amdgcn_mfma_f32_16x16x32_bf16(a0, bP[et], acc2[0][et], 0, 0, 0);
            acc2[1][et] = __builtin_amdgcn_mfma_f32_16x16x32_bf16(a1, bP[et], acc2[1][et], 0, 0, 0);
          }
        }
        if (kk < 7) {
#pragma unroll
          for (int et = 0; et < 8; et++) bP[et] = ld_frag(bBase + et * 8192 + k0 + 64);
        }
        {
          bf16x8 a0 = ld_frag(&hS[l15 * 520 + k0 + 32 + quad * 8]);
          bf16x8 a1 = ld_frag(&hS[(16 + l15) * 520 + k0 + 32 + quad * 8]);
#pragma unroll
          for (int et = 0; et < 8; et++) {
            acc2[0][et] = __builtin_amdgcn_mfma_f32_16x16x32_bf16(a0, bQ[et], acc2[0][et], 0, 0, 0);
            acc2[1][et] = __builtin_amdgcn_mfma_f32_16x16x32_bf16(a1, bQ[et], acc2[1][et], 0, 0, 0);
          }
        }
      }
    }

    // ---- masked online softmax over the 32 time rows of this pass ----
    bool ok[2][4];
#pragma unroll
    for (int mt = 0; mt < 2; mt++)
#pragma unroll
      for (int r = 0; r < 4; r++)
        ok[mt][r] = (r0 + mt * 16 + quad * 4 + r) < nvalid;

#pragma unroll
    for (int et = 0; et < 8; et++) {
      const int e = wbase + et * 16 + l15;
      float v[2][4];
      float lm = -1e30f;
#pragma unroll
      for (int mt = 0; mt < 2; mt++)
#pragma unroll
        for (int r = 0; r < 4; r++) {
          v[mt][r] = ok[mt][r] ? acc2[mt][et][r] : -1e30f;
          lm = fmaxf(lm, v[mt][r]);
        }
      lm = fmaxf(lm, __shfl_xor(lm, 16));
      lm = fmaxf(lm, __shfl_xor(lm, 32));
      float ls = 0.f, lo = 0.f;
#pragma unroll
      for (int mt = 0; mt < 2; mt++)
#pragma unroll
        for (int r = 0; r < 4; r++) {
          const float p  = __expf(v[mt][r] - lm);
          const float ev = bf2f(encA[(mt * 16 + quad * 4 + r) * 520 + e]);
          ls += p;
          lo += p * ev;
        }
      ls += __shfl_xor(ls, 16); ls += __shfl_xor(ls, 32);
      lo += __shfl_xor(lo, 16); lo += __shfl_xor(lo, 32);
      const float Mn = fmaxf(stM[et], lm);
      const float sc = __expf(stM[et] - Mn);
      const float st = __expf(lm - Mn);
      stS[et] = stS[et] * sc + ls * st;
      stO[et] = stO[et] * sc + lo * st;
      stM[et] = Mn;
    }
    __syncthreads();
  }

  if (quad == 0) {
    const size_t base = ((size_t)b * C + c) * EE;
#pragma unroll
    for (int et = 0; et < 8; et++) {
      const int e = wbase + et * 16 + l15;
      pm[base + e] = stM[et];
      ps[base + e] = stS[et];
      po[base + e] = stO[et];
    }
  }
}

// ---------------- combine over chunks ----------------
__global__ __launch_bounds__(256) void attn_combine(
    const float* __restrict__ pm, const float* __restrict__ ps,
    const float* __restrict__ po, const int* __restrict__ lens,
    float* __restrict__ out, int C, int Lc)
{
  const int b = blockIdx.x;
  const int tid = threadIdx.x;
  const int n = lens[b];
  const int cmax = min(C, (n + Lc - 1) / Lc);
#pragma unroll
  for (int half = 0; half < 2; half++) {
    const int e = tid + half * 256;
    float M = -1e30f, S = 0.f, O = 0.f;
    for (int c = 0; c < cmax; c++) {
      const size_t base = ((size_t)b * C + c) * EE;
      const float m = pm[base + e];
      const float s = ps[base + e];
      const float o = po[base + e];
      const float Mn  = fmaxf(M, m);
      const float sc0 = __expf(M - Mn);
      const float sc1 = __expf(m - Mn);
      S = S * sc0 + s * sc1;
      O = O * sc0 + o * sc1;
      M = Mn;
    }
    out[(size_t)b * EE + e] = O / S;
  }
}

extern "C" void kernel_launch(void* const* d_in, const int* in_sizes, int n_in,
                              void* d_out, int out_size, void* d_ws, size_t ws_size,
                              hipStream_t stream) {
  const float* enc  = (const float*)d_in[0];
  const int*   lens = (const int*)d_in[1];
  const float* Wh   = (const float*)d_in[2];
  const float* bh   = (const float*)d_in[3];
  const float* Wc   = (const float*)d_in[4];
  float* out = (float*)d_out;

  const size_t wbytes = (size_t)512 * 512 * sizeof(unsigned short);
  int C = 64;  // Lc=32 -> exactly one tile pass per block (load balance)
  while (C > 8 && ws_size < (size_t)3 * BB * C * EE * sizeof(float) + 2 * wbytes)
    C >>= 1;
  const int Lc = LL / C;

  float* pm = (float*)d_ws;
  float* ps = pm + (size_t)BB * C * EE;
  float* po = ps + (size_t)BB * C * EE;
  unsigned short* WhT = (unsigned short*)(po + (size_t)BB * C * EE);
  unsigned short* WcT = WhT + (size_t)512 * 512;

  prep_w<<<dim3(64, 2), 256, 0, stream>>>(Wh, Wc, WhT, WcT);
  attn_main<<<dim3(C, BB), 256, 0, stream>>>(enc, lens, WhT, bh, WcT, pm, ps, po, C, Lc);
  attn_combine<<<BB, 256, 0, stream>>>(pm, ps, po, lens, out, C, Lc);
}

// Round 4
// 1026.609 us; speedup vs baseline: 1.1484x; 1.1484x over previous
//
#include <hip/hip_runtime.h>
#include <math.h>

#define BB 32
#define LL 2048
#define EE 512
#define HH 512

typedef __bf16 bf16_t;
typedef bf16_t bf16x8 __attribute__((ext_vector_type(8)));
typedef float f32x4 __attribute__((ext_vector_type(4)));
typedef unsigned short u16x8 __attribute__((ext_vector_type(8)));

__device__ __forceinline__ unsigned short f2bf(float f) {
  unsigned int u = __builtin_bit_cast(unsigned int, f);
  unsigned int r = (u + 0x7FFFu + ((u >> 16) & 1u)) >> 16;  // RNE
  return (unsigned short)r;
}
__device__ __forceinline__ float bf2f(unsigned short s) {
  unsigned int u = ((unsigned int)s) << 16;
  return __builtin_bit_cast(float, u);
}
__device__ __forceinline__ bf16x8 ld_frag(const unsigned short* p) {
  u16x8 raw = *(const u16x8*)p;
  return __builtin_bit_cast(bf16x8, raw);
}
__device__ __forceinline__ float tanh_fast(float x) {
  x = fminf(fmaxf(x, -15.f), 15.f);
  float e2 = __expf(2.f * x);
  return (e2 - 1.f) / (e2 + 1.f);
}

// ---------------- prep: transpose + fp32->bf16 convert of Wh, Wc ----------------
// WhT[h][e] = Wh[e][h];  WcT[e][h] = Wc[h][e]   (both 512x512)
__global__ __launch_bounds__(256) void prep_w(
    const float* __restrict__ Wh, const float* __restrict__ Wc,
    unsigned short* __restrict__ WhT, unsigned short* __restrict__ WcT)
{
  const float* src = blockIdx.y ? Wc : Wh;
  unsigned short* dst = blockIdx.y ? WcT : WhT;
  const int tr = (blockIdx.x >> 3) * 64;
  const int tc = (blockIdx.x & 7) * 64;
  const int tid = threadIdx.x;
  __shared__ float tile[64][65];
  for (int i = tid; i < 64 * 16; i += 256) {
    const int r = i >> 4, c4 = (i & 15) << 2;
    const float4 v = *(const float4*)(src + (size_t)(tr + r) * 512 + tc + c4);
    tile[r][c4 + 0] = v.x; tile[r][c4 + 1] = v.y;
    tile[r][c4 + 2] = v.z; tile[r][c4 + 3] = v.w;
  }
  __syncthreads();
  for (int i = tid; i < 64 * 16; i += 256) {
    const int r = i >> 4, c4 = (i & 15) << 2;
    ushort4 pk;
    pk.x = f2bf(tile[c4 + 0][r]); pk.y = f2bf(tile[c4 + 1][r]);
    pk.z = f2bf(tile[c4 + 2][r]); pk.w = f2bf(tile[c4 + 3][r]);
    *(ushort4*)(dst + (size_t)(tc + r) * 512 + tr + c4) = pk;
  }
}

// ---------------- main: per-(b,chunk) fused GEMM1+tanh+GEMM2+online-softmax ----------------
// __launch_bounds__(256, 1): lift the VGPR allocator cap so the 2x8-fragment
// ping-pong prefetch fits in registers (~220 VGPR) instead of spilling to
// scratch (R3: VGPR capped at 128 -> 1.5 GB spill traffic, 994 us).
__global__ __launch_bounds__(256, 1) void attn_main(
    const float* __restrict__ enc, const int* __restrict__ lens,
    const unsigned short* __restrict__ WhT, const float* __restrict__ bh,
    const unsigned short* __restrict__ WcT,
    float* __restrict__ pm, float* __restrict__ ps, float* __restrict__ po,
    int C, int Lc)
{
  const int c = blockIdx.x;
  const int b = blockIdx.y;
  const int n = lens[b];
  const int l0 = c * Lc;
  const int nvalid = min(n - l0, Lc);
  if (nvalid <= 0) return;

  const int tid  = threadIdx.x;
  const int wave = tid >> 6;
  const int lane = tid & 63;
  const int quad = lane >> 4;
  const int l15  = lane & 15;
  const int wbase = wave * 128;

  __shared__ __align__(16) unsigned short encA[32 * 520];
  __shared__ __align__(16) unsigned short hS[32 * 520];
  __shared__ __align__(16) float bhS[512];

  float stM[8], stS[8], stO[8];
#pragma unroll
  for (int et = 0; et < 8; et++) { stM[et] = -1e30f; stS[et] = 0.f; stO[et] = 0.f; }

  bhS[tid] = bh[tid];
  bhS[tid + 256] = bh[tid + 256];

  for (int r0 = 0; r0 < nvalid; r0 += 32) {
    // ---- stage enc tile -> bf16 LDS ----
    const float* encRow = enc + ((size_t)b * LL + l0 + r0) * EE;
    for (int i = tid; i < 32 * 128; i += 256) {
      const int m = i >> 7, e4 = (i & 127) << 2;
      const float4 v = *(const float4*)(encRow + (size_t)m * EE + e4);
      ushort4 pk;
      pk.x = f2bf(v.x); pk.y = f2bf(v.y); pk.z = f2bf(v.z); pk.w = f2bf(v.w);
      *(ushort4*)&encA[m * 520 + e4] = pk;
    }
    __syncthreads();

    // ---- GEMM1': hT[128 x 32] per wave = WhT (A, L2) @ encT (B, LDS) ----
    f32x4 acc1[8][2];
#pragma unroll
    for (int ht = 0; ht < 8; ht++)
      for (int mt = 0; mt < 2; mt++) acc1[ht][mt] = (f32x4){0.f, 0.f, 0.f, 0.f};
    {
      const unsigned short* aBase = WhT + (size_t)(wbase + l15) * 512 + quad * 8;
      bf16x8 aP[8], aQ[8];
#pragma unroll
      for (int ht = 0; ht < 8; ht++) aP[ht] = ld_frag(aBase + ht * 8192);
#pragma unroll
      for (int kk = 0; kk < 8; kk++) {
        const int k0 = kk * 64;
        // prefetch k0+32 while computing with aP
#pragma unroll
        for (int ht = 0; ht < 8; ht++) aQ[ht] = ld_frag(aBase + ht * 8192 + k0 + 32);
        {
          bf16x8 b0 = ld_frag(&encA[l15 * 520 + k0 + quad * 8]);
          bf16x8 b1 = ld_frag(&encA[(16 + l15) * 520 + k0 + quad * 8]);
#pragma unroll
          for (int ht = 0; ht < 8; ht++) {
            acc1[ht][0] = __builtin_amdgcn_mfma_f32_16x16x32_bf16(aP[ht], b0, acc1[ht][0], 0, 0, 0);
            acc1[ht][1] = __builtin_amdgcn_mfma_f32_16x16x32_bf16(aP[ht], b1, acc1[ht][1], 0, 0, 0);
          }
        }
        if (kk < 7) {
#pragma unroll
          for (int ht = 0; ht < 8; ht++) aP[ht] = ld_frag(aBase + ht * 8192 + k0 + 64);
        }
        {
          bf16x8 b0 = ld_frag(&encA[l15 * 520 + k0 + 32 + quad * 8]);
          bf16x8 b1 = ld_frag(&encA[(16 + l15) * 520 + k0 + 32 + quad * 8]);
#pragma unroll
          for (int ht = 0; ht < 8; ht++) {
            acc1[ht][0] = __builtin_amdgcn_mfma_f32_16x16x32_bf16(aQ[ht], b0, acc1[ht][0], 0, 0, 0);
            acc1[ht][1] = __builtin_amdgcn_mfma_f32_16x16x32_bf16(aQ[ht], b1, acc1[ht][1], 0, 0, 0);
          }
        }
      }
    }

    // ---- bias + tanh, pack 4 consecutive h -> one 8B LDS write of h[m][h] ----
#pragma unroll
    for (int ht = 0; ht < 8; ht++) {
      const f32x4 bv = *(const f32x4*)&bhS[wbase + ht * 16 + quad * 4];
#pragma unroll
      for (int mt = 0; mt < 2; mt++) {
        ushort4 pk;
        pk.x = f2bf(tanh_fast(acc1[ht][mt][0] + bv[0]));
        pk.y = f2bf(tanh_fast(acc1[ht][mt][1] + bv[1]));
        pk.z = f2bf(tanh_fast(acc1[ht][mt][2] + bv[2]));
        pk.w = f2bf(tanh_fast(acc1[ht][mt][3] + bv[3]));
        *(ushort4*)&hS[(mt * 16 + l15) * 520 + wbase + ht * 16 + quad * 4] = pk;
      }
    }
    __syncthreads();

    // ---- GEMM2: logits[32 x E] = h (A, LDS) @ Wc (B = WcT, L2) ----
    f32x4 acc2[2][8];
#pragma unroll
    for (int mt = 0; mt < 2; mt++)
      for (int et = 0; et < 8; et++) acc2[mt][et] = (f32x4){0.f, 0.f, 0.f, 0.f};
    {
      const unsigned short* bBase = WcT + (size_t)(wbase + l15) * 512 + quad * 8;
      bf16x8 bP[8], bQ[8];
#pragma unroll
      for (int et = 0; et < 8; et++) bP[et] = ld_frag(bBase + et * 8192);
#pragma unroll
      for (int kk = 0; kk < 8; kk++) {
        const int k0 = kk * 64;
#pragma unroll
        for (int et = 0; et < 8; et++) bQ[et] = ld_frag(bBase + et * 8192 + k0 + 32);
        {
          bf16x8 a0 = ld_frag(&hS[l15 * 520 + k0 + quad * 8]);
          bf16x8 a1 = ld_frag(&hS[(16 + l15) * 520 + k0 + quad * 8]);
#pragma unroll
          for (int et = 0; et < 8; et++) {
            acc2[0][et] = __builtin_amdgcn_mfma_f32_16x16x32_bf16(a0, bP[et], acc2[0][et], 0, 0, 0);
            acc2[1][et] = __builtin_amdgcn_mfma_f32_16x16x32_bf16(a1, bP[et], acc2[1][et], 0, 0, 0);
          }
        }
        if (kk < 7) {
#pragma unroll
          for (int et = 0; et < 8; et++) bP[et] = ld_frag(bBase + et * 8192 + k0 + 64);
        }
        {
          bf16x8 a0 = ld_frag(&hS[l15 * 520 + k0 + 32 + quad * 8]);
          bf16x8 a1 = ld_frag(&hS[(16 + l15) * 520 + k0 + 32 + quad * 8]);
#pragma unroll
          for (int et = 0; et < 8; et++) {
            acc2[0][et] = __builtin_amdgcn_mfma_f32_16x16x32_bf16(a0, bQ[et], acc2[0][et], 0, 0, 0);
            acc2[1][et] = __builtin_amdgcn_mfma_f32_16x16x32_bf16(a1, bQ[et], acc2[1][et], 0, 0, 0);
          }
        }
      }
    }

    // ---- masked online softmax over the 32 time rows of this pass ----
    bool ok[2][4];
#pragma unroll
    for (int mt = 0; mt < 2; mt++)
#pragma unroll
      for (int r = 0; r < 4; r++)
        ok[mt][r] = (r0 + mt * 16 + quad * 4 + r) < nvalid;

#pragma unroll
    for (int et = 0; et < 8; et++) {
      const int e = wbase + et * 16 + l15;
      float v[2][4];
      float lm = -1e30f;
#pragma unroll
      for (int mt = 0; mt < 2; mt++)
#pragma unroll
        for (int r = 0; r < 4; r++) {
          v[mt][r] = ok[mt][r] ? acc2[mt][et][r] : -1e30f;
          lm = fmaxf(lm, v[mt][r]);
        }
      lm = fmaxf(lm, __shfl_xor(lm, 16));
      lm = fmaxf(lm, __shfl_xor(lm, 32));
      float ls = 0.f, lo = 0.f;
#pragma unroll
      for (int mt = 0; mt < 2; mt++)
#pragma unroll
        for (int r = 0; r < 4; r++) {
          const float p  = __expf(v[mt][r] - lm);
          const float ev = bf2f(encA[(mt * 16 + quad * 4 + r) * 520 + e]);
          ls += p;
          lo += p * ev;
        }
      ls += __shfl_xor(ls, 16); ls += __shfl_xor(ls, 32);
      lo += __shfl_xor(lo, 16); lo += __shfl_xor(lo, 32);
      const float Mn = fmaxf(stM[et], lm);
      const float sc = __expf(stM[et] - Mn);
      const float st = __expf(lm - Mn);
      stS[et] = stS[et] * sc + ls * st;
      stO[et] = stO[et] * sc + lo * st;
      stM[et] = Mn;
    }
    __syncthreads();
  }

  if (quad == 0) {
    const size_t base = ((size_t)b * C + c) * EE;
#pragma unroll
    for (int et = 0; et < 8; et++) {
      const int e = wbase + et * 16 + l15;
      pm[base + e] = stM[et];
      ps[base + e] = stS[et];
      po[base + e] = stO[et];
    }
  }
}

// ---------------- combine over chunks (parallelized: 8 e-slabs x 4 c-groups) ----------------
__global__ __launch_bounds__(256) void attn_combine(
    const float* __restrict__ pm, const float* __restrict__ ps,
    const float* __restrict__ po, const int* __restrict__ lens,
    float* __restrict__ out, int C, int Lc)
{
  const int b  = blockIdx.y;
  const int e  = blockIdx.x * 64 + (threadIdx.x & 63);
  const int g  = threadIdx.x >> 6;  // c-group 0..3
  const int n  = lens[b];
  const int cmax = min(C, (n + Lc - 1) / Lc);

  float M = -1e30f, S = 0.f, O = 0.f;
  for (int c = g; c < cmax; c += 4) {
    const size_t base = ((size_t)b * C + c) * EE;
    const float m = pm[base + e];
    const float s = ps[base + e];
    const float o = po[base + e];
    const float Mn  = fmaxf(M, m);
    const float sc0 = __expf(M - Mn);
    const float sc1 = __expf(m - Mn);
    S = S * sc0 + s * sc1;
    O = O * sc0 + o * sc1;
    M = Mn;
  }

  __shared__ float sM[4][64], sS[4][64], sO[4][64];
  sM[g][threadIdx.x & 63] = M;
  sS[g][threadIdx.x & 63] = S;
  sO[g][threadIdx.x & 63] = O;
  __syncthreads();

  if (g == 0) {
    const int le = threadIdx.x & 63;
    float Mt = sM[0][le], St = sS[0][le], Ot = sO[0][le];
#pragma unroll
    for (int gg = 1; gg < 4; gg++) {
      const float m = sM[gg][le];
      const float Mn  = fmaxf(Mt, m);
      const float sc0 = __expf(Mt - Mn);
      const float sc1 = __expf(m - Mn);
      St = St * sc0 + sS[gg][le] * sc1;
      Ot = Ot * sc0 + sO[gg][le] * sc1;
      Mt = Mn;
    }
    out[(size_t)b * EE + e] = Ot / St;  // St > 0: c=0 always valid (lengths >= 1)
  }
}

extern "C" void kernel_launch(void* const* d_in, const int* in_sizes, int n_in,
                              void* d_out, int out_size, void* d_ws, size_t ws_size,
                              hipStream_t stream) {
  const float* enc  = (const float*)d_in[0];
  const int*   lens = (const int*)d_in[1];
  const float* Wh   = (const float*)d_in[2];
  const float* bh   = (const float*)d_in[3];
  const float* Wc   = (const float*)d_in[4];
  float* out = (float*)d_out;

  const size_t wbytes = (size_t)512 * 512 * sizeof(unsigned short);
  int C = 64;  // Lc=32 -> exactly one tile pass per block (load balance)
  while (C > 8 && ws_size < (size_t)3 * BB * C * EE * sizeof(float) + 2 * wbytes)
    C >>= 1;
  const int Lc = LL / C;

  float* pm = (float*)d_ws;
  float* ps = pm + (size_t)BB * C * EE;
  float* po = ps + (size_t)BB * C * EE;
  unsigned short* WhT = (unsigned short*)(po + (size_t)BB * C * EE);
  unsigned short* WcT = WhT + (size_t)512 * 512;

  prep_w<<<dim3(64, 2), 256, 0, stream>>>(Wh, Wc, WhT, WcT);
  attn_main<<<dim3(C, BB), 256, 0, stream>>>(enc, lens, WhT, bh, WcT, pm, ps, po, C, Lc);
  attn_combine<<<dim3(8, BB), 256, 0, stream>>>(pm, ps, po, lens, out, C, Lc);
}

// Round 5
// 398.884 us; speedup vs baseline: 2.9555x; 2.5737x over previous
//
#include <hip/hip_runtime.h>
#include <math.h>

#define BB 32
#define LL 2048
#define EE 512
#define HH 512

typedef __bf16 bf16_t;
typedef bf16_t bf16x8 __attribute__((ext_vector_type(8)));
typedef float f32x4 __attribute__((ext_vector_type(4)));
typedef unsigned short u16x8 __attribute__((ext_vector_type(8)));

__device__ __forceinline__ unsigned short f2bf(float f) {
  unsigned int u = __builtin_bit_cast(unsigned int, f);
  unsigned int r = (u + 0x7FFFu + ((u >> 16) & 1u)) >> 16;  // RNE
  return (unsigned short)r;
}
__device__ __forceinline__ float bf2f(unsigned short s) {
  unsigned int u = ((unsigned int)s) << 16;
  return __builtin_bit_cast(float, u);
}
__device__ __forceinline__ bf16x8 ld_frag(const unsigned short* p) {
  u16x8 raw = *(const u16x8*)p;
  return __builtin_bit_cast(bf16x8, raw);
}
__device__ __forceinline__ float tanh_fast(float x) {
  x = fminf(fmaxf(x, -15.f), 15.f);
  float e2 = __expf(2.f * x);
  return (e2 - 1.f) / (e2 + 1.f);
}

// ---------------- prep: transpose + fp32->bf16 convert of Wh, Wc ----------------
// WhT[h][e] = Wh[e][h];  WcT[e][h] = Wc[h][e]   (both 512x512)
__global__ __launch_bounds__(256) void prep_w(
    const float* __restrict__ Wh, const float* __restrict__ Wc,
    unsigned short* __restrict__ WhT, unsigned short* __restrict__ WcT)
{
  const float* src = blockIdx.y ? Wc : Wh;
  unsigned short* dst = blockIdx.y ? WcT : WhT;
  const int tr = (blockIdx.x >> 3) * 64;
  const int tc = (blockIdx.x & 7) * 64;
  const int tid = threadIdx.x;
  __shared__ float tile[64][65];
  for (int i = tid; i < 64 * 16; i += 256) {
    const int r = i >> 4, c4 = (i & 15) << 2;
    const float4 v = *(const float4*)(src + (size_t)(tr + r) * 512 + tc + c4);
    tile[r][c4 + 0] = v.x; tile[r][c4 + 1] = v.y;
    tile[r][c4 + 2] = v.z; tile[r][c4 + 3] = v.w;
  }
  __syncthreads();
  for (int i = tid; i < 64 * 16; i += 256) {
    const int r = i >> 4, c4 = (i & 15) << 2;
    ushort4 pk;
    pk.x = f2bf(tile[c4 + 0][r]); pk.y = f2bf(tile[c4 + 1][r]);
    pk.z = f2bf(tile[c4 + 2][r]); pk.w = f2bf(tile[c4 + 3][r]);
    *(ushort4*)(dst + (size_t)(tc + r) * 512 + tr + c4) = pk;
  }
}

// ---------------- main: 512 threads = 8 waves, each wave owns a 64-wide h/e slab ----------------
// Per-wave register budget ~110 (<128 cap of launch_bounds(512,4) => 4 waves/SIMD,
// 2 blocks/CU). k-loop is "#pragma unroll 1" + depth-1 ping-pong: exactly one
// k-step of weight loads in flight — prevents the R3/R4 load-hoisting spill.
__global__ __launch_bounds__(512, 4) void attn_main(
    const float* __restrict__ enc, const int* __restrict__ lens,
    const unsigned short* __restrict__ WhT, const float* __restrict__ bh,
    const unsigned short* __restrict__ WcT,
    float* __restrict__ pm, float* __restrict__ ps, float* __restrict__ po,
    int C, int Lc)
{
  const int c = blockIdx.x;
  const int b = blockIdx.y;
  const int n = lens[b];
  const int l0 = c * Lc;
  const int nvalid = min(n - l0, Lc);
  if (nvalid <= 0) return;

  const int tid  = threadIdx.x;
  const int wave = tid >> 6;       // 0..7
  const int lane = tid & 63;
  const int quad = lane >> 4;
  const int l15  = lane & 15;
  const int wbase = wave * 64;     // wave's 64-wide h-slab (GEMM1) / e-slab (GEMM2)

  __shared__ __align__(16) unsigned short encA[32 * 520];
  __shared__ __align__(16) unsigned short hS[32 * 520];
  __shared__ __align__(16) float bhS[512];

  float stM[4], stS[4], stO[4];
#pragma unroll
  for (int et = 0; et < 4; et++) { stM[et] = -1e30f; stS[et] = 0.f; stO[et] = 0.f; }

  bhS[tid] = bh[tid];

  for (int r0 = 0; r0 < nvalid; r0 += 32) {
    // ---- stage enc tile -> bf16 LDS (one copy shared by 8 waves) ----
    const float* encRow = enc + ((size_t)b * LL + l0 + r0) * EE;
    for (int i = tid; i < 32 * 128; i += 512) {
      const int m = i >> 7, e4 = (i & 127) << 2;
      const float4 v = *(const float4*)(encRow + (size_t)m * EE + e4);
      ushort4 pk;
      pk.x = f2bf(v.x); pk.y = f2bf(v.y); pk.z = f2bf(v.z); pk.w = f2bf(v.w);
      *(ushort4*)&encA[m * 520 + e4] = pk;
    }
    __syncthreads();

    // ---- GEMM1': hT[64 x 32] per wave = WhT (A, L2) @ encT (B, LDS) ----
    f32x4 acc1[4][2];
#pragma unroll
    for (int t = 0; t < 4; t++)
      for (int mt = 0; mt < 2; mt++) acc1[t][mt] = (f32x4){0.f, 0.f, 0.f, 0.f};
    {
      const unsigned short* aBase = WhT + (size_t)(wbase + l15) * 512 + quad * 8;
      bf16x8 aC[4];
#pragma unroll
      for (int t = 0; t < 4; t++) aC[t] = ld_frag(aBase + t * 8192);
#pragma unroll 1
      for (int kk = 0; kk < 15; kk++) {
        const int k0 = kk * 32;
        bf16x8 aN[4];
#pragma unroll
        for (int t = 0; t < 4; t++) aN[t] = ld_frag(aBase + t * 8192 + k0 + 32);
        const bf16x8 b0 = ld_frag(&encA[l15 * 520 + k0 + quad * 8]);
        const bf16x8 b1 = ld_frag(&encA[(16 + l15) * 520 + k0 + quad * 8]);
#pragma unroll
        for (int t = 0; t < 4; t++) {
          acc1[t][0] = __builtin_amdgcn_mfma_f32_16x16x32_bf16(aC[t], b0, acc1[t][0], 0, 0, 0);
          acc1[t][1] = __builtin_amdgcn_mfma_f32_16x16x32_bf16(aC[t], b1, acc1[t][1], 0, 0, 0);
        }
#pragma unroll
        for (int t = 0; t < 4; t++) aC[t] = aN[t];
      }
      {  // peeled last k-step
        const int k0 = 15 * 32;
        const bf16x8 b0 = ld_frag(&encA[l15 * 520 + k0 + quad * 8]);
        const bf16x8 b1 = ld_frag(&encA[(16 + l15) * 520 + k0 + quad * 8]);
#pragma unroll
        for (int t = 0; t < 4; t++) {
          acc1[t][0] = __builtin_amdgcn_mfma_f32_16x16x32_bf16(aC[t], b0, acc1[t][0], 0, 0, 0);
          acc1[t][1] = __builtin_amdgcn_mfma_f32_16x16x32_bf16(aC[t], b1, acc1[t][1], 0, 0, 0);
        }
      }
    }

    // ---- bias + tanh, pack 4 consecutive h -> one 8B LDS write of h[m][h] ----
#pragma unroll
    for (int t = 0; t < 4; t++) {
      const f32x4 bv = *(const f32x4*)&bhS[wbase + t * 16 + quad * 4];
#pragma unroll
      for (int mt = 0; mt < 2; mt++) {
        ushort4 pk;
        pk.x = f2bf(tanh_fast(acc1[t][mt][0] + bv[0]));
        pk.y = f2bf(tanh_fast(acc1[t][mt][1] + bv[1]));
        pk.z = f2bf(tanh_fast(acc1[t][mt][2] + bv[2]));
        pk.w = f2bf(tanh_fast(acc1[t][mt][3] + bv[3]));
        *(ushort4*)&hS[(mt * 16 + l15) * 520 + wbase + t * 16 + quad * 4] = pk;
      }
    }
    __syncthreads();

    // ---- GEMM2: logits[32 x 64] per wave = h (A, LDS) @ Wc (B = WcT, L2) ----
    f32x4 acc2[2][4];
#pragma unroll
    for (int mt = 0; mt < 2; mt++)
      for (int et = 0; et < 4; et++) acc2[mt][et] = (f32x4){0.f, 0.f, 0.f, 0.f};
    {
      const unsigned short* bBase = WcT + (size_t)(wbase + l15) * 512 + quad * 8;
      bf16x8 bC[4];
#pragma unroll
      for (int et = 0; et < 4; et++) bC[et] = ld_frag(bBase + et * 8192);
#pragma unroll 1
      for (int kk = 0; kk < 15; kk++) {
        const int k0 = kk * 32;
        bf16x8 bN[4];
#pragma unroll
        for (int et = 0; et < 4; et++) bN[et] = ld_frag(bBase + et * 8192 + k0 + 32);
        const bf16x8 a0 = ld_frag(&hS[l15 * 520 + k0 + quad * 8]);
        const bf16x8 a1 = ld_frag(&hS[(16 + l15) * 520 + k0 + quad * 8]);
#pragma unroll
        for (int et = 0; et < 4; et++) {
          acc2[0][et] = __builtin_amdgcn_mfma_f32_16x16x32_bf16(a0, bC[et], acc2[0][et], 0, 0, 0);
          acc2[1][et] = __builtin_amdgcn_mfma_f32_16x16x32_bf16(a1, bC[et], acc2[1][et], 0, 0, 0);
        }
#pragma unroll
        for (int et = 0; et < 4; et++) bC[et] = bN[et];
      }
      {  // peeled last k-step
        const int k0 = 15 * 32;
        const bf16x8 a0 = ld_frag(&hS[l15 * 520 + k0 + quad * 8]);
        const bf16x8 a1 = ld_frag(&hS[(16 + l15) * 520 + k0 + quad * 8]);
#pragma unroll
        for (int et = 0; et < 4; et++) {
          acc2[0][et] = __builtin_amdgcn_mfma_f32_16x16x32_bf16(a0, bC[et], acc2[0][et], 0, 0, 0);
          acc2[1][et] = __builtin_amdgcn_mfma_f32_16x16x32_bf16(a1, bC[et], acc2[1][et], 0, 0, 0);
        }
      }
    }

    // ---- masked online softmax over the 32 time rows of this pass ----
    bool ok[2][4];
#pragma unroll
    for (int mt = 0; mt < 2; mt++)
#pragma unroll
      for (int r = 0; r < 4; r++)
        ok[mt][r] = (r0 + mt * 16 + quad * 4 + r) < nvalid;

#pragma unroll
    for (int et = 0; et < 4; et++) {
      const int e = wbase + et * 16 + l15;
      float v[2][4];
      float lm = -1e30f;
#pragma unroll
      for (int mt = 0; mt < 2; mt++)
#pragma unroll
        for (int r = 0; r < 4; r++) {
          v[mt][r] = ok[mt][r] ? acc2[mt][et][r] : -1e30f;
          lm = fmaxf(lm, v[mt][r]);
        }
      lm = fmaxf(lm, __shfl_xor(lm, 16));
      lm = fmaxf(lm, __shfl_xor(lm, 32));
      float ls = 0.f, lo = 0.f;
#pragma unroll
      for (int mt = 0; mt < 2; mt++)
#pragma unroll
        for (int r = 0; r < 4; r++) {
          const float p  = __expf(v[mt][r] - lm);
          const float ev = bf2f(encA[(mt * 16 + quad * 4 + r) * 520 + e]);
          ls += p;
          lo += p * ev;
        }
      ls += __shfl_xor(ls, 16); ls += __shfl_xor(ls, 32);
      lo += __shfl_xor(lo, 16); lo += __shfl_xor(lo, 32);
      const float Mn = fmaxf(stM[et], lm);
      const float sc = __expf(stM[et] - Mn);
      const float st = __expf(lm - Mn);
      stS[et] = stS[et] * sc + ls * st;
      stO[et] = stO[et] * sc + lo * st;
      stM[et] = Mn;
    }
    __syncthreads();
  }

  if (quad == 0) {
    const size_t base = ((size_t)b * C + c) * EE;
#pragma unroll
    for (int et = 0; et < 4; et++) {
      const int e = wbase + et * 16 + l15;
      pm[base + e] = stM[et];
      ps[base + e] = stS[et];
      po[base + e] = stO[et];
    }
  }
}

// ---------------- combine over chunks (parallelized: 8 e-slabs x 4 c-groups) ----------------
__global__ __launch_bounds__(256) void attn_combine(
    const float* __restrict__ pm, const float* __restrict__ ps,
    const float* __restrict__ po, const int* __restrict__ lens,
    float* __restrict__ out, int C, int Lc)
{
  const int b  = blockIdx.y;
  const int e  = blockIdx.x * 64 + (threadIdx.x & 63);
  const int g  = threadIdx.x >> 6;  // c-group 0..3
  const int n  = lens[b];
  const int cmax = min(C, (n + Lc - 1) / Lc);

  float M = -1e30f, S = 0.f, O = 0.f;
  for (int c = g; c < cmax; c += 4) {
    const size_t base = ((size_t)b * C + c) * EE;
    const float m = pm[base + e];
    const float s = ps[base + e];
    const float o = po[base + e];
    const float Mn  = fmaxf(M, m);
    const float sc0 = __expf(M - Mn);
    const float sc1 = __expf(m - Mn);
    S = S * sc0 + s * sc1;
    O = O * sc0 + o * sc1;
    M = Mn;
  }

  __shared__ float sM[4][64], sS[4][64], sO[4][64];
  sM[g][threadIdx.x & 63] = M;
  sS[g][threadIdx.x & 63] = S;
  sO[g][threadIdx.x & 63] = O;
  __syncthreads();

  if (g == 0) {
    const int le = threadIdx.x & 63;
    float Mt = sM[0][le], St = sS[0][le], Ot = sO[0][le];
#pragma unroll
    for (int gg = 1; gg < 4; gg++) {
      const float m = sM[gg][le];
      const float Mn  = fmaxf(Mt, m);
      const float sc0 = __expf(Mt - Mn);
      const float sc1 = __expf(m - Mn);
      St = St * sc0 + sS[gg][le] * sc1;
      Ot = Ot * sc0 + sO[gg][le] * sc1;
      Mt = Mn;
    }
    out[(size_t)b * EE + e] = Ot / St;  // St > 0: c=0 always valid (lengths >= 1)
  }
}

extern "C" void kernel_launch(void* const* d_in, const int* in_sizes, int n_in,
                              void* d_out, int out_size, void* d_ws, size_t ws_size,
                              hipStream_t stream) {
  const float* enc  = (const float*)d_in[0];
  const int*   lens = (const int*)d_in[1];
  const float* Wh   = (const float*)d_in[2];
  const float* bh   = (const float*)d_in[3];
  const float* Wc   = (const float*)d_in[4];
  float* out = (float*)d_out;

  const size_t wbytes = (size_t)512 * 512 * sizeof(unsigned short);
  int C = 64;  // Lc=32 -> exactly one tile pass per block (load balance)
  while (C > 8 && ws_size < (size_t)3 * BB * C * EE * sizeof(float) + 2 * wbytes)
    C >>= 1;
  const int Lc = LL / C;

  float* pm = (float*)d_ws;
  float* ps = pm + (size_t)BB * C * EE;
  float* po = ps + (size_t)BB * C * EE;
  unsigned short* WhT = (unsigned short*)(po + (size_t)BB * C * EE);
  unsigned short* WcT = WhT + (size_t)512 * 512;

  prep_w<<<dim3(64, 2), 256, 0, stream>>>(Wh, Wc, WhT, WcT);
  attn_main<<<dim3(C, BB), 512, 0, stream>>>(enc, lens, WhT, bh, WcT, pm, ps, po, C, Lc);
  attn_combine<<<dim3(8, BB), 256, 0, stream>>>(pm, ps, po, lens, out, C, Lc);
}

// Round 6
// 333.689 us; speedup vs baseline: 3.5330x; 1.1954x over previous
//
#include <hip/hip_runtime.h>
#include <math.h>

#define BB 32
#define LL 2048
#define EE 512
#define HH 512
#define WSL 40   // padded LDS row stride (ushorts) for weight slabs: 80 B -> <=2-way banks (free)

typedef __bf16 bf16_t;
typedef bf16_t bf16x8 __attribute__((ext_vector_type(8)));
typedef float f32x4 __attribute__((ext_vector_type(4)));
typedef unsigned short u16x8 __attribute__((ext_vector_type(8)));

__device__ __forceinline__ unsigned short f2bf(float f) {
  unsigned int u = __builtin_bit_cast(unsigned int, f);
  unsigned int r = (u + 0x7FFFu + ((u >> 16) & 1u)) >> 16;  // RNE
  return (unsigned short)r;
}
__device__ __forceinline__ float bf2f(unsigned short s) {
  unsigned int u = ((unsigned int)s) << 16;
  return __builtin_bit_cast(float, u);
}
__device__ __forceinline__ bf16x8 ld_frag(const unsigned short* p) {
  u16x8 raw = *(const u16x8*)p;
  return __builtin_bit_cast(bf16x8, raw);
}
__device__ __forceinline__ float tanh_fast(float x) {
  x = fminf(fmaxf(x, -15.f), 15.f);
  float e2 = __expf(2.f * x);
  return (e2 - 1.f) / (e2 + 1.f);
}

// issue the 4 global 16B loads for one 64-row x 32-k weight slab (wave-private rows)
__device__ __forceinline__ void w_issue(const unsigned short* __restrict__ Wt,
                                        int rbase, int k0, int lane, u16x8 t[4]) {
  const unsigned short* g = Wt + (size_t)(rbase + (lane >> 2)) * 512 + k0 + (lane & 3) * 8;
#pragma unroll
  for (int i = 0; i < 4; i++) t[i] = *(const u16x8*)(g + i * 16 * 512);
}
// write the slab into this wave's LDS buffer (padded row stride WSL)
__device__ __forceinline__ void w_write(unsigned short* buf, int lane, const u16x8 t[4]) {
  unsigned short* d = buf + (lane >> 2) * WSL + (lane & 3) * 8;
#pragma unroll
  for (int i = 0; i < 4; i++) *(u16x8*)(d + i * 16 * WSL) = t[i];
}

// ---------------- prep: transpose + fp32->bf16 convert of Wh, Wc ----------------
// WhT[h][e] = Wh[e][h];  WcT[e][h] = Wc[h][e]   (both 512x512)
__global__ __launch_bounds__(256) void prep_w(
    const float* __restrict__ Wh, const float* __restrict__ Wc,
    unsigned short* __restrict__ WhT, unsigned short* __restrict__ WcT)
{
  const float* src = blockIdx.y ? Wc : Wh;
  unsigned short* dst = blockIdx.y ? WcT : WhT;
  const int tr = (blockIdx.x >> 3) * 64;
  const int tc = (blockIdx.x & 7) * 64;
  const int tid = threadIdx.x;
  __shared__ float tile[64][65];
  for (int i = tid; i < 64 * 16; i += 256) {
    const int r = i >> 4, c4 = (i & 15) << 2;
    const float4 v = *(const float4*)(src + (size_t)(tr + r) * 512 + tc + c4);
    tile[r][c4 + 0] = v.x; tile[r][c4 + 1] = v.y;
    tile[r][c4 + 2] = v.z; tile[r][c4 + 3] = v.w;
  }
  __syncthreads();
  for (int i = tid; i < 64 * 16; i += 256) {
    const int r = i >> 4, c4 = (i & 15) << 2;
    ushort4 pk;
    pk.x = f2bf(tile[c4 + 0][r]); pk.y = f2bf(tile[c4 + 1][r]);
    pk.z = f2bf(tile[c4 + 2][r]); pk.w = f2bf(tile[c4 + 3][r]);
    *(ushort4*)(dst + (size_t)(tc + r) * 512 + tr + c4) = pk;
  }
}

// ---------------- main: 512 thr = 8 waves; weights pipelined global->LDS (wave-private dbuf) ----------------
// k-loops have NO barriers: each wave stages and consumes only its own 64-row slab.
// Loads lead ds_writes by one half-step, writes lead frag-reads by one half-step
// -> MFMAs never gate on vmcnt of fresh L2 loads (the R2/R5 stall).
__global__ __launch_bounds__(512, 2) void attn_main(
    const float* __restrict__ enc, const int* __restrict__ lens,
    const unsigned short* __restrict__ WhT, const float* __restrict__ bh,
    const unsigned short* __restrict__ WcT,
    float* __restrict__ pm, float* __restrict__ ps, float* __restrict__ po,
    int C, int Lc)
{
  const int c = blockIdx.x;
  const int b = blockIdx.y;
  const int n = lens[b];
  const int l0 = c * Lc;
  const int nvalid = min(n - l0, Lc);
  if (nvalid <= 0) return;

  const int tid  = threadIdx.x;
  const int wave = tid >> 6;       // 0..7
  const int lane = tid & 63;
  const int quad = lane >> 4;
  const int l15  = lane & 15;
  const int wbase = wave * 64;     // wave's 64-wide h-slab (GEMM1) / e-slab (GEMM2)

  __shared__ __align__(16) unsigned short encA[32 * 520];          // 33.3 KB
  __shared__ __align__(16) unsigned short hS[32 * 520];            // 33.3 KB
  __shared__ __align__(16) unsigned short wslabS[8 * 2 * 64 * WSL];// 80 KB (8 waves x 2 bufs)
  __shared__ __align__(16) float bhS[512];

  unsigned short* buf0 = &wslabS[(wave * 2 + 0) * 64 * WSL];
  unsigned short* buf1 = &wslabS[(wave * 2 + 1) * 64 * WSL];

  float stM[4], stS[4], stO[4];
#pragma unroll
  for (int et = 0; et < 4; et++) { stM[et] = -1e30f; stS[et] = 0.f; stO[et] = 0.f; }

  bhS[tid] = bh[tid];

  for (int r0 = 0; r0 < nvalid; r0 += 32) {
    // ---- stage enc tile -> bf16 LDS (one copy shared by 8 waves) ----
    const float* encRow = enc + ((size_t)b * LL + l0 + r0) * EE;
    for (int i = tid; i < 32 * 128; i += 512) {
      const int m = i >> 7, e4 = (i & 127) << 2;
      const float4 v = *(const float4*)(encRow + (size_t)m * EE + e4);
      ushort4 pk;
      pk.x = f2bf(v.x); pk.y = f2bf(v.y); pk.z = f2bf(v.z); pk.w = f2bf(v.w);
      *(ushort4*)&encA[m * 520 + e4] = pk;
    }
    __syncthreads();

    // ================= GEMM1: hT[64 x 32] per wave = WhT @ encT =================
    f32x4 acc1[4][2];
#pragma unroll
    for (int t = 0; t < 4; t++)
      for (int mt = 0; mt < 2; mt++) acc1[t][mt] = (f32x4){0.f, 0.f, 0.f, 0.f};
    {
      u16x8 tA[4], tB[4];
      w_issue(WhT, wbase, 0, lane, tA);
      w_issue(WhT, wbase, 32, lane, tB);
      w_write(buf0, lane, tA);          // waits only tA's loads; tB stays in flight
#pragma unroll 1
      for (int kk = 0; kk < 16; kk += 2) {
        // even half: write slab kk+1 (tB), issue loads kk+2 (tA), consume buf0 (slab kk)
        w_write(buf1, lane, tB);
        if (kk + 2 < 16) w_issue(WhT, wbase, (kk + 2) * 32, lane, tA);
        {
          const int k0 = kk * 32;
          const bf16x8 b0 = ld_frag(&encA[l15 * 520 + k0 + quad * 8]);
          const bf16x8 b1 = ld_frag(&encA[(16 + l15) * 520 + k0 + quad * 8]);
#pragma unroll
          for (int t = 0; t < 4; t++) {
            const bf16x8 af = ld_frag(&buf0[(t * 16 + l15) * WSL + quad * 8]);
            acc1[t][0] = __builtin_amdgcn_mfma_f32_16x16x32_bf16(af, b0, acc1[t][0], 0, 0, 0);
            acc1[t][1] = __builtin_amdgcn_mfma_f32_16x16x32_bf16(af, b1, acc1[t][1], 0, 0, 0);
          }
        }
        // odd half: write slab kk+2 (tA), issue loads kk+3 (tB), consume buf1 (slab kk+1)
        if (kk + 2 < 16) w_write(buf0, lane, tA);
        if (kk + 3 < 16) w_issue(WhT, wbase, (kk + 3) * 32, lane, tB);
        {
          const int k0 = (kk + 1) * 32;
          const bf16x8 b0 = ld_frag(&encA[l15 * 520 + k0 + quad * 8]);
          const bf16x8 b1 = ld_frag(&encA[(16 + l15) * 520 + k0 + quad * 8]);
#pragma unroll
          for (int t = 0; t < 4; t++) {
            const bf16x8 af = ld_frag(&buf1[(t * 16 + l15) * WSL + quad * 8]);
            acc1[t][0] = __builtin_amdgcn_mfma_f32_16x16x32_bf16(af, b0, acc1[t][0], 0, 0, 0);
            acc1[t][1] = __builtin_amdgcn_mfma_f32_16x16x32_bf16(af, b1, acc1[t][1], 0, 0, 0);
          }
        }
      }
    }

    // ---- bias + tanh, pack 4 consecutive h -> one 8B LDS write of h[m][h] ----
#pragma unroll
    for (int t = 0; t < 4; t++) {
      const f32x4 bv = *(const f32x4*)&bhS[wbase + t * 16 + quad * 4];
#pragma unroll
      for (int mt = 0; mt < 2; mt++) {
        ushort4 pk;
        pk.x = f2bf(tanh_fast(acc1[t][mt][0] + bv[0]));
        pk.y = f2bf(tanh_fast(acc1[t][mt][1] + bv[1]));
        pk.z = f2bf(tanh_fast(acc1[t][mt][2] + bv[2]));
        pk.w = f2bf(tanh_fast(acc1[t][mt][3] + bv[3]));
        *(ushort4*)&hS[(mt * 16 + l15) * 520 + wbase + t * 16 + quad * 4] = pk;
      }
    }
    __syncthreads();

    // ================= GEMM2: logits[32 x 64] per wave = h @ WcT-slab =================
    f32x4 acc2[2][4];
#pragma unroll
    for (int mt = 0; mt < 2; mt++)
      for (int et = 0; et < 4; et++) acc2[mt][et] = (f32x4){0.f, 0.f, 0.f, 0.f};
    {
      u16x8 tA[4], tB[4];
      w_issue(WcT, wbase, 0, lane, tA);
      w_issue(WcT, wbase, 32, lane, tB);
      w_write(buf0, lane, tA);
#pragma unroll 1
      for (int kk = 0; kk < 16; kk += 2) {
        w_write(buf1, lane, tB);
        if (kk + 2 < 16) w_issue(WcT, wbase, (kk + 2) * 32, lane, tA);
        {
          const int k0 = kk * 32;
          const bf16x8 a0 = ld_frag(&hS[l15 * 520 + k0 + quad * 8]);
          const bf16x8 a1 = ld_frag(&hS[(16 + l15) * 520 + k0 + quad * 8]);
#pragma unroll
          for (int et = 0; et < 4; et++) {
            const bf16x8 bf = ld_frag(&buf0[(et * 16 + l15) * WSL + quad * 8]);
            acc2[0][et] = __builtin_amdgcn_mfma_f32_16x16x32_bf16(a0, bf, acc2[0][et], 0, 0, 0);
            acc2[1][et] = __builtin_amdgcn_mfma_f32_16x16x32_bf16(a1, bf, acc2[1][et], 0, 0, 0);
          }
        }
        if (kk + 2 < 16) w_write(buf0, lane, tA);
        if (kk + 3 < 16) w_issue(WcT, wbase, (kk + 3) * 32, lane, tB);
        {
          const int k0 = (kk + 1) * 32;
          const bf16x8 a0 = ld_frag(&hS[l15 * 520 + k0 + quad * 8]);
          const bf16x8 a1 = ld_frag(&hS[(16 + l15) * 520 + k0 + quad * 8]);
#pragma unroll
          for (int et = 0; et < 4; et++) {
            const bf16x8 bf = ld_frag(&buf1[(et * 16 + l15) * WSL + quad * 8]);
            acc2[0][et] = __builtin_amdgcn_mfma_f32_16x16x32_bf16(a0, bf, acc2[0][et], 0, 0, 0);
            acc2[1][et] = __builtin_amdgcn_mfma_f32_16x16x32_bf16(a1, bf, acc2[1][et], 0, 0, 0);
          }
        }
      }
    }

    // ---- masked online softmax over the 32 time rows of this pass ----
    bool ok[2][4];
#pragma unroll
    for (int mt = 0; mt < 2; mt++)
#pragma unroll
      for (int r = 0; r < 4; r++)
        ok[mt][r] = (r0 + mt * 16 + quad * 4 + r) < nvalid;

#pragma unroll
    for (int et = 0; et < 4; et++) {
      const int e = wbase + et * 16 + l15;
      float v[2][4];
      float lm = -1e30f;
#pragma unroll
      for (int mt = 0; mt < 2; mt++)
#pragma unroll
        for (int r = 0; r < 4; r++) {
          v[mt][r] = ok[mt][r] ? acc2[mt][et][r] : -1e30f;
          lm = fmaxf(lm, v[mt][r]);
        }
      lm = fmaxf(lm, __shfl_xor(lm, 16));
      lm = fmaxf(lm, __shfl_xor(lm, 32));
      float ls = 0.f, lo = 0.f;
#pragma unroll
      for (int mt = 0; mt < 2; mt++)
#pragma unroll
        for (int r = 0; r < 4; r++) {
          const float p  = __expf(v[mt][r] - lm);
          const float ev = bf2f(encA[(mt * 16 + quad * 4 + r) * 520 + e]);
          ls += p;
          lo += p * ev;
        }
      ls += __shfl_xor(ls, 16); ls += __shfl_xor(ls, 32);
      lo += __shfl_xor(lo, 16); lo += __shfl_xor(lo, 32);
      const float Mn = fmaxf(stM[et], lm);
      const float sc = __expf(stM[et] - Mn);
      const float st = __expf(lm - Mn);
      stS[et] = stS[et] * sc + ls * st;
      stO[et] = stO[et] * sc + lo * st;
      stM[et] = Mn;
    }
    __syncthreads();
  }

  if (quad == 0) {
    const size_t base = ((size_t)b * C + c) * EE;
#pragma unroll
    for (int et = 0; et < 4; et++) {
      const int e = wbase + et * 16 + l15;
      pm[base + e] = stM[et];
      ps[base + e] = stS[et];
      po[base + e] = stO[et];
    }
  }
}

// ---------------- combine over chunks (parallelized: 8 e-slabs x 4 c-groups) ----------------
__global__ __launch_bounds__(256) void attn_combine(
    const float* __restrict__ pm, const float* __restrict__ ps,
    const float* __restrict__ po, const int* __restrict__ lens,
    float* __restrict__ out, int C, int Lc)
{
  const int b  = blockIdx.y;
  const int e  = blockIdx.x * 64 + (threadIdx.x & 63);
  const int g  = threadIdx.x >> 6;  // c-group 0..3
  const int n  = lens[b];
  const int cmax = min(C, (n + Lc - 1) / Lc);

  float M = -1e30f, S = 0.f, O = 0.f;
  for (int c = g; c < cmax; c += 4) {
    const size_t base = ((size_t)b * C + c) * EE;
    const float m = pm[base + e];
    const float s = ps[base + e];
    const float o = po[base + e];
    const float Mn  = fmaxf(M, m);
    const float sc0 = __expf(M - Mn);
    const float sc1 = __expf(m - Mn);
    S = S * sc0 + s * sc1;
    O = O * sc0 + o * sc1;
    M = Mn;
  }

  __shared__ float sM[4][64], sS[4][64], sO[4][64];
  sM[g][threadIdx.x & 63] = M;
  sS[g][threadIdx.x & 63] = S;
  sO[g][threadIdx.x & 63] = O;
  __syncthreads();

  if (g == 0) {
    const int le = threadIdx.x & 63;
    float Mt = sM[0][le], St = sS[0][le], Ot = sO[0][le];
#pragma unroll
    for (int gg = 1; gg < 4; gg++) {
      const float m = sM[gg][le];
      const float Mn  = fmaxf(Mt, m);
      const float sc0 = __expf(Mt - Mn);
      const float sc1 = __expf(m - Mn);
      St = St * sc0 + sS[gg][le] * sc1;
      Ot = Ot * sc0 + sO[gg][le] * sc1;
      Mt = Mn;
    }
    out[(size_t)b * EE + e] = Ot / St;  // St > 0: c=0 always valid (lengths >= 1)
  }
}

extern "C" void kernel_launch(void* const* d_in, const int* in_sizes, int n_in,
                              void* d_out, int out_size, void* d_ws, size_t ws_size,
                              hipStream_t stream) {
  const float* enc  = (const float*)d_in[0];
  const int*   lens = (const int*)d_in[1];
  const float* Wh   = (const float*)d_in[2];
  const float* bh   = (const float*)d_in[3];
  const float* Wc   = (const float*)d_in[4];
  float* out = (float*)d_out;

  const size_t wbytes = (size_t)512 * 512 * sizeof(unsigned short);
  int C = 64;  // Lc=32 -> exactly one tile pass per block (load balance)
  while (C > 8 && ws_size < (size_t)3 * BB * C * EE * sizeof(float) + 2 * wbytes)
    C >>= 1;
  const int Lc = LL / C;

  float* pm = (float*)d_ws;
  float* ps = pm + (size_t)BB * C * EE;
  float* po = ps + (size_t)BB * C * EE;
  unsigned short* WhT = (unsigned short*)(po + (size_t)BB * C * EE);
  unsigned short* WcT = WhT + (size_t)512 * 512;

  prep_w<<<dim3(64, 2), 256, 0, stream>>>(Wh, Wc, WhT, WcT);
  attn_main<<<dim3(C, BB), 512, 0, stream>>>(enc, lens, WhT, bh, WcT, pm, ps, po, C, Lc);
  attn_combine<<<dim3(8, BB), 256, 0, stream>>>(pm, ps, po, lens, out, C, Lc);
}

// Round 7
// 291.521 us; speedup vs baseline: 4.0440x; 1.1446x over previous
//
#include <hip/hip_runtime.h>
#include <math.h>

#define BB 32
#define LL 2048
#define EE 512
#define HH 512
#define WSL 32   // packed slab row stride (ushorts): 64B rows, lane-sequential writes,
                 // bank-uniform b128 frag reads (R6's WSL=40 pad measured 15.7M conflict-cycles)

typedef __bf16 bf16_t;
typedef bf16_t bf16x8 __attribute__((ext_vector_type(8)));
typedef float f32x4 __attribute__((ext_vector_type(4)));
typedef unsigned short u16x8 __attribute__((ext_vector_type(8)));

__device__ __forceinline__ unsigned short f2bf(float f) {
  unsigned int u = __builtin_bit_cast(unsigned int, f);
  unsigned int r = (u + 0x7FFFu + ((u >> 16) & 1u)) >> 16;  // RNE
  return (unsigned short)r;
}
__device__ __forceinline__ float bf2f(unsigned short s) {
  unsigned int u = ((unsigned int)s) << 16;
  return __builtin_bit_cast(float, u);
}
__device__ __forceinline__ bf16x8 ld_frag(const unsigned short* p) {
  u16x8 raw = *(const u16x8*)p;
  return __builtin_bit_cast(bf16x8, raw);
}
__device__ __forceinline__ float tanh_fast(float x) {
  x = fminf(fmaxf(x, -15.f), 15.f);
  float e2 = __expf(2.f * x);
  return (e2 - 1.f) / (e2 + 1.f);
}

// issue the 4 global 16B loads for one 64-row x 32-k weight slab (wave-private rows)
__device__ __forceinline__ void w_issue(const unsigned short* __restrict__ Wt,
                                        int rbase, int k0, int lane, u16x8 t[4]) {
  const unsigned short* g = Wt + (size_t)(rbase + (lane >> 2)) * 512 + k0 + (lane & 3) * 8;
#pragma unroll
  for (int i = 0; i < 4; i++) t[i] = *(const u16x8*)(g + i * 16 * 512);
}
// write the slab into this wave's LDS buffer: offset = lane*16B (perfectly sequential)
__device__ __forceinline__ void w_write(unsigned short* buf, int lane, const u16x8 t[4]) {
  unsigned short* d = buf + (lane >> 2) * WSL + (lane & 3) * 8;
#pragma unroll
  for (int i = 0; i < 4; i++) *(u16x8*)(d + i * 16 * WSL) = t[i];
}

// ---------------- prep: transpose + fp32->bf16 convert of Wh, Wc; init work queue ----------------
__global__ __launch_bounds__(256) void prep_w(
    const float* __restrict__ Wh, const float* __restrict__ Wc,
    unsigned short* __restrict__ WhT, unsigned short* __restrict__ WcT,
    int* __restrict__ q)
{
  if (blockIdx.x == 0 && blockIdx.y == 0 && threadIdx.x == 0) *q = 0;
  const float* src = blockIdx.y ? Wc : Wh;
  unsigned short* dst = blockIdx.y ? WcT : WhT;
  const int tr = (blockIdx.x >> 3) * 64;
  const int tc = (blockIdx.x & 7) * 64;
  const int tid = threadIdx.x;
  __shared__ float tile[64][65];
  for (int i = tid; i < 64 * 16; i += 256) {
    const int r = i >> 4, c4 = (i & 15) << 2;
    const float4 v = *(const float4*)(src + (size_t)(tr + r) * 512 + tc + c4);
    tile[r][c4 + 0] = v.x; tile[r][c4 + 1] = v.y;
    tile[r][c4 + 2] = v.z; tile[r][c4 + 3] = v.w;
  }
  __syncthreads();
  for (int i = tid; i < 64 * 16; i += 256) {
    const int r = i >> 4, c4 = (i & 15) << 2;
    ushort4 pk;
    pk.x = f2bf(tile[c4 + 0][r]); pk.y = f2bf(tile[c4 + 1][r]);
    pk.z = f2bf(tile[c4 + 2][r]); pk.w = f2bf(tile[c4 + 3][r]);
    *(ushort4*)(dst + (size_t)(tc + r) * 512 + tr + c4) = pk;
  }
}

// ---------------- main: persistent blocks pop (b,c) items; k-loop rotated per (item,wave) ----------------
// Rotation: concurrent waves read DIFFERENT 4KB k-windows of the shared weight
// matrices -> no chip-wide same-address L2 hot set (theory for the R2/R5/R6 plateau).
__global__ __launch_bounds__(512, 2) void attn_main(
    const float* __restrict__ enc, const int* __restrict__ lens,
    const unsigned short* __restrict__ WhT, const float* __restrict__ bh,
    const unsigned short* __restrict__ WcT,
    float* __restrict__ pm, float* __restrict__ ps, float* __restrict__ po,
    int* __restrict__ q, int C, int Lc)
{
  const int tid  = threadIdx.x;
  const int wave = tid >> 6;       // 0..7
  const int lane = tid & 63;
  const int quad = lane >> 4;
  const int l15  = lane & 15;
  const int wbase = wave * 64;     // wave's 64-wide h-slab (GEMM1) / e-slab (GEMM2)

  __shared__ __align__(16) unsigned short encA[32 * 520];            // 33.3 KB
  __shared__ __align__(16) unsigned short hS[32 * 520];              // 33.3 KB
  __shared__ __align__(16) unsigned short wslabS[8 * 2 * 64 * WSL];  // 64 KB
  __shared__ __align__(16) float bhS[512];
  __shared__ int itemS;

  unsigned short* buf0 = &wslabS[(wave * 2 + 0) * 64 * WSL];
  unsigned short* buf1 = &wslabS[(wave * 2 + 1) * 64 * WSL];

  bhS[tid] = bh[tid];
  const int nitems = 32 * C;

#pragma unroll 1
  for (;;) {
    __syncthreads();                       // protect itemS + LDS from previous item
    if (tid == 0) itemS = atomicAdd(q, 1);
    __syncthreads();
    const int item = itemS;
    if (item >= nitems) break;            // uniform across block
    const int b = item & 31;
    const int c = item >> 5;
    const int n = lens[b];
    const int l0 = c * Lc;
    const int nvalid = min(n - l0, Lc);
    if (nvalid <= 0) continue;

    const int phase = (item + wave) & 15;  // k-window de-phasing

    float stM[4], stS[4], stO[4];
#pragma unroll
    for (int et = 0; et < 4; et++) { stM[et] = -1e30f; stS[et] = 0.f; stO[et] = 0.f; }

#pragma unroll 1
    for (int r0 = 0; r0 < nvalid; r0 += 32) {
      // ---- stage enc tile -> bf16 LDS (one copy shared by 8 waves) ----
      const float* encRow = enc + ((size_t)b * LL + l0 + r0) * EE;
      for (int i = tid; i < 32 * 128; i += 512) {
        const int m = i >> 7, e4 = (i & 127) << 2;
        const float4 v = *(const float4*)(encRow + (size_t)m * EE + e4);
        ushort4 pk;
        pk.x = f2bf(v.x); pk.y = f2bf(v.y); pk.z = f2bf(v.z); pk.w = f2bf(v.w);
        *(ushort4*)&encA[m * 520 + e4] = pk;
      }
      __syncthreads();

      // ================= GEMM1: hT[64 x 32] per wave = WhT @ encT =================
      f32x4 acc1[4][2];
#pragma unroll
      for (int t = 0; t < 4; t++)
        for (int mt = 0; mt < 2; mt++) acc1[t][mt] = (f32x4){0.f, 0.f, 0.f, 0.f};
      {
        u16x8 tA[4], tB[4];
        w_issue(WhT, wbase, ((0 + phase) & 15) * 32, lane, tA);
        w_issue(WhT, wbase, ((1 + phase) & 15) * 32, lane, tB);
        w_write(buf0, lane, tA);          // waits only tA's loads; tB stays in flight
#pragma unroll 1
        for (int kk = 0; kk < 16; kk += 2) {
          w_write(buf1, lane, tB);
          if (kk + 2 < 16) w_issue(WhT, wbase, ((kk + 2 + phase) & 15) * 32, lane, tA);
          {
            const int k0 = ((kk + phase) & 15) * 32;
            const bf16x8 b0 = ld_frag(&encA[l15 * 520 + k0 + quad * 8]);
            const bf16x8 b1 = ld_frag(&encA[(16 + l15) * 520 + k0 + quad * 8]);
#pragma unroll
            for (int t = 0; t < 4; t++) {
              const bf16x8 af = ld_frag(&buf0[(t * 16 + l15) * WSL + quad * 8]);
              acc1[t][0] = __builtin_amdgcn_mfma_f32_16x16x32_bf16(af, b0, acc1[t][0], 0, 0, 0);
              acc1[t][1] = __builtin_amdgcn_mfma_f32_16x16x32_bf16(af, b1, acc1[t][1], 0, 0, 0);
            }
          }
          if (kk + 2 < 16) w_write(buf0, lane, tA);
          if (kk + 3 < 16) w_issue(WhT, wbase, ((kk + 3 + phase) & 15) * 32, lane, tB);
          {
            const int k0 = ((kk + 1 + phase) & 15) * 32;
            const bf16x8 b0 = ld_frag(&encA[l15 * 520 + k0 + quad * 8]);
            const bf16x8 b1 = ld_frag(&encA[(16 + l15) * 520 + k0 + quad * 8]);
#pragma unroll
            for (int t = 0; t < 4; t++) {
              const bf16x8 af = ld_frag(&buf1[(t * 16 + l15) * WSL + quad * 8]);
              acc1[t][0] = __builtin_amdgcn_mfma_f32_16x16x32_bf16(af, b0, acc1[t][0], 0, 0, 0);
              acc1[t][1] = __builtin_amdgcn_mfma_f32_16x16x32_bf16(af, b1, acc1[t][1], 0, 0, 0);
            }
          }
        }
      }

      // ---- bias + tanh, pack 4 consecutive h -> one 8B LDS write of h[m][h] ----
#pragma unroll
      for (int t = 0; t < 4; t++) {
        const f32x4 bv = *(const f32x4*)&bhS[wbase + t * 16 + quad * 4];
#pragma unroll
        for (int mt = 0; mt < 2; mt++) {
          ushort4 pk;
          pk.x = f2bf(tanh_fast(acc1[t][mt][0] + bv[0]));
          pk.y = f2bf(tanh_fast(acc1[t][mt][1] + bv[1]));
          pk.z = f2bf(tanh_fast(acc1[t][mt][2] + bv[2]));
          pk.w = f2bf(tanh_fast(acc1[t][mt][3] + bv[3]));
          *(ushort4*)&hS[(mt * 16 + l15) * 520 + wbase + t * 16 + quad * 4] = pk;
        }
      }
      __syncthreads();

      // ================= GEMM2: logits[32 x 64] per wave = h @ WcT-slab =================
      f32x4 acc2[2][4];
#pragma unroll
      for (int mt = 0; mt < 2; mt++)
        for (int et = 0; et < 4; et++) acc2[mt][et] = (f32x4){0.f, 0.f, 0.f, 0.f};
      {
        u16x8 tA[4], tB[4];
        w_issue(WcT, wbase, ((0 + phase) & 15) * 32, lane, tA);
        w_issue(WcT, wbase, ((1 + phase) & 15) * 32, lane, tB);
        w_write(buf0, lane, tA);
#pragma unroll 1
        for (int kk = 0; kk < 16; kk += 2) {
          w_write(buf1, lane, tB);
          if (kk + 2 < 16) w_issue(WcT, wbase, ((kk + 2 + phase) & 15) * 32, lane, tA);
          {
            const int k0 = ((kk + phase) & 15) * 32;
            const bf16x8 a0 = ld_frag(&hS[l15 * 520 + k0 + quad * 8]);
            const bf16x8 a1 = ld_frag(&hS[(16 + l15) * 520 + k0 + quad * 8]);
#pragma unroll
            for (int et = 0; et < 4; et++) {
              const bf16x8 bf = ld_frag(&buf0[(et * 16 + l15) * WSL + quad * 8]);
              acc2[0][et] = __builtin_amdgcn_mfma_f32_16x16x32_bf16(a0, bf, acc2[0][et], 0, 0, 0);
              acc2[1][et] = __builtin_amdgcn_mfma_f32_16x16x32_bf16(a1, bf, acc2[1][et], 0, 0, 0);
            }
          }
          if (kk + 2 < 16) w_write(buf0, lane, tA);
          if (kk + 3 < 16) w_issue(WcT, wbase, ((kk + 3 + phase) & 15) * 32, lane, tB);
          {
            const int k0 = ((kk + 1 + phase) & 15) * 32;
            const bf16x8 a0 = ld_frag(&hS[l15 * 520 + k0 + quad * 8]);
            const bf16x8 a1 = ld_frag(&hS[(16 + l15) * 520 + k0 + quad * 8]);
#pragma unroll
            for (int et = 0; et < 4; et++) {
              const bf16x8 bf = ld_frag(&buf1[(et * 16 + l15) * WSL + quad * 8]);
              acc2[0][et] = __builtin_amdgcn_mfma_f32_16x16x32_bf16(a0, bf, acc2[0][et], 0, 0, 0);
              acc2[1][et] = __builtin_amdgcn_mfma_f32_16x16x32_bf16(a1, bf, acc2[1][et], 0, 0, 0);
            }
          }
        }
      }

      // ---- masked online softmax over the 32 time rows of this pass ----
      bool ok[2][4];
#pragma unroll
      for (int mt = 0; mt < 2; mt++)
#pragma unroll
        for (int r = 0; r < 4; r++)
          ok[mt][r] = (r0 + mt * 16 + quad * 4 + r) < nvalid;

#pragma unroll
      for (int et = 0; et < 4; et++) {
        const int e = wbase + et * 16 + l15;
        float v[2][4];
        float lm = -1e30f;
#pragma unroll
        for (int mt = 0; mt < 2; mt++)
#pragma unroll
          for (int r = 0; r < 4; r++) {
            v[mt][r] = ok[mt][r] ? acc2[mt][et][r] : -1e30f;
            lm = fmaxf(lm, v[mt][r]);
          }
        lm = fmaxf(lm, __shfl_xor(lm, 16));
        lm = fmaxf(lm, __shfl_xor(lm, 32));
        float ls = 0.f, lo = 0.f;
#pragma unroll
        for (int mt = 0; mt < 2; mt++)
#pragma unroll
          for (int r = 0; r < 4; r++) {
            const float p  = __expf(v[mt][r] - lm);
            const float ev = bf2f(encA[(mt * 16 + quad * 4 + r) * 520 + e]);
            ls += p;
            lo += p * ev;
          }
        ls += __shfl_xor(ls, 16); ls += __shfl_xor(ls, 32);
        lo += __shfl_xor(lo, 16); lo += __shfl_xor(lo, 32);
        const float Mn = fmaxf(stM[et], lm);
        const float sc = __expf(stM[et] - Mn);
        const float st = __expf(lm - Mn);
        stS[et] = stS[et] * sc + ls * st;
        stO[et] = stO[et] * sc + lo * st;
        stM[et] = Mn;
      }
      __syncthreads();
    }

    if (quad == 0) {
      const size_t base = ((size_t)b * C + c) * EE;
#pragma unroll
      for (int et = 0; et < 4; et++) {
        const int e = wbase + et * 16 + l15;
        pm[base + e] = stM[et];
        ps[base + e] = stS[et];
        po[base + e] = stO[et];
      }
    }
  }
}

// ---------------- combine over chunks (parallelized: 8 e-slabs x 4 c-groups) ----------------
__global__ __launch_bounds__(256) void attn_combine(
    const float* __restrict__ pm, const float* __restrict__ ps,
    const float* __restrict__ po, const int* __restrict__ lens,
    float* __restrict__ out, int C, int Lc)
{
  const int b  = blockIdx.y;
  const int e  = blockIdx.x * 64 + (threadIdx.x & 63);
  const int g  = threadIdx.x >> 6;  // c-group 0..3
  const int n  = lens[b];
  const int cmax = min(C, (n + Lc - 1) / Lc);

  float M = -1e30f, S = 0.f, O = 0.f;
  for (int c = g; c < cmax; c += 4) {
    const size_t base = ((size_t)b * C + c) * EE;
    const float m = pm[base + e];
    const float s = ps[base + e];
    const float o = po[base + e];
    const float Mn  = fmaxf(M, m);
    const float sc0 = __expf(M - Mn);
    const float sc1 = __expf(m - Mn);
    S = S * sc0 + s * sc1;
    O = O * sc0 + o * sc1;
    M = Mn;
  }

  __shared__ float sM[4][64], sS[4][64], sO[4][64];
  sM[g][threadIdx.x & 63] = M;
  sS[g][threadIdx.x & 63] = S;
  sO[g][threadIdx.x & 63] = O;
  __syncthreads();

  if (g == 0) {
    const int le = threadIdx.x & 63;
    float Mt = sM[0][le], St = sS[0][le], Ot = sO[0][le];
#pragma unroll
    for (int gg = 1; gg < 4; gg++) {
      const float m = sM[gg][le];
      const float Mn  = fmaxf(Mt, m);
      const float sc0 = __expf(Mt - Mn);
      const float sc1 = __expf(m - Mn);
      St = St * sc0 + sS[gg][le] * sc1;
      Ot = Ot * sc0 + sO[gg][le] * sc1;
      Mt = Mn;
    }
    out[(size_t)b * EE + e] = Ot / St;  // St > 0: c=0 always valid (lengths >= 1)
  }
}

extern "C" void kernel_launch(void* const* d_in, const int* in_sizes, int n_in,
                              void* d_out, int out_size, void* d_ws, size_t ws_size,
                              hipStream_t stream) {
  const float* enc  = (const float*)d_in[0];
  const int*   lens = (const int*)d_in[1];
  const float* Wh   = (const float*)d_in[2];
  const float* bh   = (const float*)d_in[3];
  const float* Wc   = (const float*)d_in[4];
  float* out = (float*)d_out;

  const size_t wbytes = (size_t)512 * 512 * sizeof(unsigned short);
  int C = 64;  // Lc=32 -> one 32-row pass per item
  while (C > 8 && ws_size < (size_t)3 * BB * C * EE * sizeof(float) + 2 * wbytes + 64)
    C >>= 1;
  const int Lc = LL / C;

  float* pm = (float*)d_ws;
  float* ps = pm + (size_t)BB * C * EE;
  float* po = ps + (size_t)BB * C * EE;
  unsigned short* WhT = (unsigned short*)(po + (size_t)BB * C * EE);
  unsigned short* WcT = WhT + (size_t)512 * 512;
  int* q = (int*)(WcT + (size_t)512 * 512);

  prep_w<<<dim3(64, 2), 256, 0, stream>>>(Wh, Wc, WhT, WcT, q);
  attn_main<<<dim3(512), 512, 0, stream>>>(enc, lens, WhT, bh, WcT, pm, ps, po, q, C, Lc);
  attn_combine<<<dim3(8, BB), 256, 0, stream>>>(pm, ps, po, lens, out, C, Lc);
}